// Round 5
// baseline (4251.844 us; speedup 1.0000x reference)
//
#include <hip/hip_runtime.h>

// Problem constants (match reference)
#define NG   4
#define NU   200000
#define NI   100000
#define DD   64
#define NNZE 1000000
#define NB   4096

__device__ __forceinline__ float lrelu(float x) { return fmaxf(x, 0.5f * x); }

// Copy graph-k embeddings into working buffers (float4 vectorized).
__global__ __launch_bounds__(256) void copy_kern(const float* __restrict__ ue,
                                                 const float* __restrict__ ie,
                                                 float* __restrict__ cu,
                                                 float* __restrict__ ci) {
    size_t idx = (size_t)blockIdx.x * 256 + threadIdx.x;
    const size_t nu4 = (size_t)NU * DD / 4, ni4 = (size_t)NI * DD / 4;
    if (idx < nu4) {
        reinterpret_cast<float4*>(cu)[idx] = reinterpret_cast<const float4*>(ue)[idx];
    } else if (idx < nu4 + ni4) {
        size_t j = idx - nu4;
        reinterpret_cast<float4*>(ci)[j] = reinterpret_cast<const float4*>(ie)[j];
    }
}

// Fused both-direction edge scatter: one 64-lane wave per edge.
// Edges [0, NNZE): items->users via subadj.  [NNZE, 2*NNZE): users->items via subtpadj.
__global__ __launch_bounds__(256) void scatter_kern(const float* __restrict__ cu,
                                                    const float* __restrict__ ci,
                                                    float* __restrict__ au,
                                                    float* __restrict__ ai,
                                                    const int* __restrict__ sa_src,
                                                    const int* __restrict__ sa_tgt,
                                                    const int* __restrict__ st_src,
                                                    const int* __restrict__ st_tgt) {
    long long t = (long long)blockIdx.x * 256 + threadIdx.x;
    int d = (int)(t & 63);
    long long e = t >> 6;
    if (e < NNZE) {
        int s = sa_src[e], g = sa_tgt[e];
        atomicAdd(au + (long long)g * DD + d, ci[(long long)s * DD + d]);
    } else {
        long long e2 = e - NNZE;
        if (e2 < NNZE) {
            int s = st_src[e2], g = st_tgt[e2];
            atomicAdd(ai + (long long)g * DD + d, cu[(long long)s * DD + d]);
        }
    }
}

// cur = lrelu(agg) + cur, for both user and item buffers (float4).
__global__ __launch_bounds__(256) void update_kern(float* __restrict__ cu,
                                                   float* __restrict__ ci,
                                                   const float* __restrict__ au,
                                                   const float* __restrict__ ai) {
    size_t idx = (size_t)blockIdx.x * 256 + threadIdx.x;
    const size_t nu4 = (size_t)NU * DD / 4, ni4 = (size_t)NI * DD / 4;
    if (idx < nu4) {
        float4 a = reinterpret_cast<const float4*>(au)[idx];
        float4 c = reinterpret_cast<float4*>(cu)[idx];
        c.x += lrelu(a.x); c.y += lrelu(a.y); c.z += lrelu(a.z); c.w += lrelu(a.w);
        reinterpret_cast<float4*>(cu)[idx] = c;
    } else if (idx < nu4 + ni4) {
        size_t j = idx - nu4;
        float4 a = reinterpret_cast<const float4*>(ai)[j];
        float4 c = reinterpret_cast<float4*>(ci)[j];
        c.x += lrelu(a.x); c.y += lrelu(a.y); c.z += lrelu(a.z); c.w += lrelu(a.w);
        reinterpret_cast<float4*>(ci)[j] = c;
    }
}

// Accumulate the sampled rows of the current stage into compact [NB,64] buffers.
// su += cur_u[uids], sl += cur_u[ulocs], si += cur_i[iids].
__global__ __launch_bounds__(256) void gacc_kern(const float* __restrict__ cu,
                                                 const float* __restrict__ ci,
                                                 const int* __restrict__ uids,
                                                 const int* __restrict__ iids,
                                                 const int* __restrict__ ulocs,
                                                 float* __restrict__ su,
                                                 float* __restrict__ si,
                                                 float* __restrict__ sl) {
    int t = blockIdx.x * 256 + threadIdx.x;
    if (t >= NB * DD) return;
    int b = t >> 6, d = t & 63;
    su[t] += cu[(long long)uids[b] * DD + d];
    sl[t] += cu[(long long)ulocs[b] * DD + d];
    si[t] += ci[(long long)iids[b] * DD + d];
}

// preds[b] = dot(su/4, si/4) + dot(lrelu(sl), si/4); wave-64 reduction per b.
__global__ __launch_bounds__(256) void final_kern(const float* __restrict__ su,
                                                  const float* __restrict__ sl,
                                                  const float* __restrict__ si,
                                                  float* __restrict__ out) {
    int t = blockIdx.x * 256 + threadIdx.x;   // NB*DD threads
    int b = t >> 6;
    float s_i = si[t];
    float p = su[t] * s_i * (1.0f / 16.0f) + lrelu(sl[t]) * s_i * 0.25f;
    #pragma unroll
    for (int off = 32; off >= 1; off >>= 1) p += __shfl_down(p, off);
    if ((t & 63) == 0) out[b] = p;
}

extern "C" void kernel_launch(void* const* d_in, const int* in_sizes, int n_in,
                              void* d_out, int out_size, void* d_ws, size_t ws_size,
                              hipStream_t stream) {
    (void)in_sizes; (void)n_in; (void)out_size; (void)ws_size;

    const float* ue      = (const float*)d_in[0];  // [G,U,D]
    const float* ie      = (const float*)d_in[1];  // [G,I,D]
    const int*   sa_src  = (const int*)d_in[2];    // [G,NNZ] item idx
    const int*   sa_tgt  = (const int*)d_in[3];    // [G,NNZ] user idx
    const int*   st_src  = (const int*)d_in[4];    // [G,NNZ] user idx
    const int*   st_tgt  = (const int*)d_in[5];    // [G,NNZ] item idx
    const int*   uids    = (const int*)d_in[6];    // [B]
    const int*   iids    = (const int*)d_in[7];    // [B]
    const int*   ulocs   = (const int*)d_in[8];    // [B]

    float* ws = (float*)d_ws;
    float* cu = ws;                                // U*D
    float* ci = cu + (size_t)NU * DD;              // I*D
    float* au = ci + (size_t)NI * DD;              // U*D   (agg_u, contiguous with ai)
    float* ai = au + (size_t)NU * DD;              // I*D
    float* su = ai + (size_t)NI * DD;              // NB*DD
    float* sl = su + (size_t)NB * DD;
    float* si = sl + (size_t)NB * DD;

    const size_t nElem4 = ((size_t)NU * DD + (size_t)NI * DD) / 4;  // float4 count
    const int copyBlocks    = (int)((nElem4 + 255) / 256);
    const int scatterBlocks = (int)((2LL * NNZE * 64) / 256);
    const int gaccBlocks    = (NB * DD) / 256;

    // zero the three batch accumulators (contiguous)
    hipMemsetAsync(su, 0, (size_t)3 * NB * DD * sizeof(float), stream);

    for (int k = 0; k < NG; ++k) {
        copy_kern<<<copyBlocks, 256, 0, stream>>>(ue + (size_t)k * NU * DD,
                                                  ie + (size_t)k * NI * DD, cu, ci);
        gacc_kern<<<gaccBlocks, 256, 0, stream>>>(cu, ci, uids, iids, ulocs, su, si, sl);
        for (int l = 0; l < 2; ++l) {
            hipMemsetAsync(au, 0,
                           ((size_t)NU * DD + (size_t)NI * DD) * sizeof(float), stream);
            scatter_kern<<<scatterBlocks, 256, 0, stream>>>(
                cu, ci, au, ai,
                sa_src + (size_t)k * NNZE, sa_tgt + (size_t)k * NNZE,
                st_src + (size_t)k * NNZE, st_tgt + (size_t)k * NNZE);
            update_kern<<<copyBlocks, 256, 0, stream>>>(cu, ci, au, ai);
            gacc_kern<<<gaccBlocks, 256, 0, stream>>>(cu, ci, uids, iids, ulocs, su, si, sl);
        }
    }

    final_kern<<<gaccBlocks, 256, 0, stream>>>(su, sl, si, (float*)d_out);
}

// Round 8
// 2011.793 us; speedup vs baseline: 2.1135x; 2.1135x over previous
//
#include <hip/hip_runtime.h>

// Problem constants (match reference)
#define NG   4
#define NU   200000
#define NI   100000
#define DD   64
#define NNZE 1000000
#define NB   4096

// scan chunking
#define CH      256
#define CHU     ((NU + CH - 1) / CH)        // 782 chunks per user array
#define CHI     ((NI + CH - 1) / CH)        // 391 chunks per item array
#define NCHUNKS (NG * CHU + NG * CHI)       // 4692

__device__ __forceinline__ float lrelu(float x) { return fmaxf(x, 0.5f * x); }

// ---------------- CSR build ----------------
// Edge slot mapping for hist/fill: s in [0, 2*NG*NNZE)
//   g = s / (2*NNZE); rem = s % (2*NNZE); dir = rem < NNZE ? user-dir : item-dir

__global__ __launch_bounds__(256) void hist_kern(const int* __restrict__ sa_tgt,
                                                 const int* __restrict__ st_tgt,
                                                 int* __restrict__ cnt_u,
                                                 int* __restrict__ cnt_i) {
    long long s = (long long)blockIdx.x * 256 + threadIdx.x;
    if (s >= 2LL * NG * NNZE) return;
    int g = (int)(s / (2LL * NNZE));
    long long rem = s - (long long)g * (2LL * NNZE);
    if (rem < NNZE) {
        int t = sa_tgt[(long long)g * NNZE + rem];
        atomicAdd(&cnt_u[(long long)g * NU + t], 1);
    } else {
        int t = st_tgt[(long long)g * NNZE + (rem - NNZE)];
        atomicAdd(&cnt_i[(long long)g * NI + t], 1);
    }
}

// per-chunk sums
__global__ __launch_bounds__(256) void scan1_kern(const int* __restrict__ cnt_u,
                                                  const int* __restrict__ cnt_i,
                                                  int* __restrict__ csum) {
    int cb = blockIdx.x, tid = threadIdx.x;
    const int* arr; int N, local;
    if (cb < NG * CHU) {
        int a = cb / CHU; local = cb - a * CHU;
        arr = cnt_u + (long long)a * NU; N = NU;
    } else {
        int c2 = cb - NG * CHU;
        int a = c2 / CHI; local = c2 - a * CHI;
        arr = cnt_i + (long long)a * NI; N = NI;
    }
    int idx = local * CH + tid;
    int v = (idx < N) ? arr[idx] : 0;
    __shared__ int sh[256];
    sh[tid] = v; __syncthreads();
    for (int off = 128; off > 0; off >>= 1) {
        if (tid < off) sh[tid] += sh[tid + off];
        __syncthreads();
    }
    if (tid == 0) csum[cb] = sh[0];
}

// exclusive-scan the chunk sums of each of the 8 arrays; write rp[N] = total
__global__ __launch_bounds__(256) void scan2_kern(int* __restrict__ csum,
                                                  int* __restrict__ rp_u,
                                                  int* __restrict__ rp_i) {
    int a = blockIdx.x, tid = threadIdx.x;
    int base, nc; int* rpN;
    if (a < NG) { base = a * CHU; nc = CHU; rpN = rp_u + (long long)a * (NU + 1) + NU; }
    else        { base = NG * CHU + (a - NG) * CHI; nc = CHI;
                  rpN = rp_i + (long long)(a - NG) * (NI + 1) + NI; }
    __shared__ int sh[256];
    int carry = 0;
    for (int t0 = 0; t0 < nc; t0 += 256) {
        int i = t0 + tid;
        int v = (i < nc) ? csum[base + i] : 0;
        sh[tid] = v; __syncthreads();
        for (int off = 1; off < 256; off <<= 1) {
            int t = (tid >= off) ? sh[tid - off] : 0;
            __syncthreads();
            sh[tid] += t;
            __syncthreads();
        }
        int incl = sh[tid];
        int total = sh[255];
        if (i < nc) csum[base + i] = incl - v + carry;
        carry += total;
        __syncthreads();
    }
    if (tid == 0) *rpN = carry;
}

// row_ptr[idx] = scanned_chunk_offset + intra-chunk exclusive prefix
__global__ __launch_bounds__(256) void scan3_kern(const int* __restrict__ cnt_u,
                                                  const int* __restrict__ cnt_i,
                                                  const int* __restrict__ csum,
                                                  int* __restrict__ rp_u,
                                                  int* __restrict__ rp_i) {
    int cb = blockIdx.x, tid = threadIdx.x;
    const int* arr; int* rp; int N, local;
    if (cb < NG * CHU) {
        int a = cb / CHU; local = cb - a * CHU;
        arr = cnt_u + (long long)a * NU; rp = rp_u + (long long)a * (NU + 1); N = NU;
    } else {
        int c2 = cb - NG * CHU;
        int a = c2 / CHI; local = c2 - a * CHI;
        arr = cnt_i + (long long)a * NI; rp = rp_i + (long long)a * (NI + 1); N = NI;
    }
    int idx = local * CH + tid;
    int v = (idx < N) ? arr[idx] : 0;
    __shared__ int sh[256];
    sh[tid] = v; __syncthreads();
    for (int off = 1; off < 256; off <<= 1) {
        int t = (tid >= off) ? sh[tid - off] : 0;
        __syncthreads();
        sh[tid] += t;
        __syncthreads();
    }
    if (idx < N) rp[idx] = csum[cb] + sh[tid] - v;
}

// scatter edge sources into CSR col arrays (cnt_* re-zeroed as cursors)
__global__ __launch_bounds__(256) void fill_kern(const int* __restrict__ sa_src,
                                                 const int* __restrict__ sa_tgt,
                                                 const int* __restrict__ st_src,
                                                 const int* __restrict__ st_tgt,
                                                 const int* __restrict__ rp_u,
                                                 const int* __restrict__ rp_i,
                                                 int* __restrict__ cnt_u,
                                                 int* __restrict__ cnt_i,
                                                 int* __restrict__ cl_u,
                                                 int* __restrict__ cl_i) {
    long long s = (long long)blockIdx.x * 256 + threadIdx.x;
    if (s >= 2LL * NG * NNZE) return;
    int g = (int)(s / (2LL * NNZE));
    long long rem = s - (long long)g * (2LL * NNZE);
    if (rem < NNZE) {
        long long e = (long long)g * NNZE + rem;
        int t = sa_tgt[e], src = sa_src[e];
        int pos = rp_u[(long long)g * (NU + 1) + t] + atomicAdd(&cnt_u[(long long)g * NU + t], 1);
        cl_u[(long long)g * NNZE + pos] = src;
    } else {
        long long e = (long long)g * NNZE + (rem - NNZE);
        int t = st_tgt[e], src = st_src[e];
        int pos = rp_i[(long long)g * (NI + 1) + t] + atomicAdd(&cnt_i[(long long)g * NI + t], 1);
        cl_i[(long long)g * NNZE + pos] = src;
    }
}

// ---------------- layer 1: full gather-aggregate, fused lrelu+residual ----------------
// one 64-lane wave per target row; rows [0,NU) = users, [NU,NU+NI) = items
__global__ __launch_bounds__(256) void layer1_kern(const float* __restrict__ ue_k,
                                                   const float* __restrict__ ie_k,
                                                   const int* __restrict__ rp_u,
                                                   const int* __restrict__ rp_i,
                                                   const int* __restrict__ cl_u,
                                                   const int* __restrict__ cl_i,
                                                   float* __restrict__ cu1,
                                                   float* __restrict__ ci1) {
    long long t = (long long)blockIdx.x * 256 + threadIdx.x;
    int lane = (int)(t & 63);
    long long w = t >> 6;
    if (w < NU) {
        int r = (int)w;
        int b0 = rp_u[r], b1 = rp_u[r + 1];
        float acc = 0.f;
        for (int j = b0; j < b1; ++j) {
            int c = cl_u[j];
            acc += ie_k[(long long)c * DD + lane];
        }
        cu1[(long long)r * DD + lane] = lrelu(acc) + ue_k[(long long)r * DD + lane];
    } else if (w < (long long)NU + NI) {
        int r = (int)(w - NU);
        int b0 = rp_i[r], b1 = rp_i[r + 1];
        float acc = 0.f;
        for (int j = b0; j < b1; ++j) {
            int c = cl_i[j];
            acc += ue_k[(long long)c * DD + lane];
        }
        ci1[(long long)r * DD + lane] = lrelu(acc) + ie_k[(long long)r * DD + lane];
    }
}

// ---------------- layer 2 at sampled rows only, + accumulate ----------------
// sum over stages = e0 + 2*e1 + lrelu(agg2);  e1 = cu1/ci1, agg2 gathers layer-1 results.
// waves: kind 0 -> su (uids), kind 1 -> sl (ulocs), kind 2 -> si (iids)
__global__ __launch_bounds__(256) void samp_kern(const float* __restrict__ ue_k,
                                                 const float* __restrict__ ie_k,
                                                 const int* __restrict__ rp_u,
                                                 const int* __restrict__ rp_i,
                                                 const int* __restrict__ cl_u,
                                                 const int* __restrict__ cl_i,
                                                 const float* __restrict__ cu1,
                                                 const float* __restrict__ ci1,
                                                 const int* __restrict__ uids,
                                                 const int* __restrict__ iids,
                                                 const int* __restrict__ ulocs,
                                                 float* __restrict__ su,
                                                 float* __restrict__ si,
                                                 float* __restrict__ sl) {
    int t = blockIdx.x * 256 + threadIdx.x;   // 3*NB*64 threads
    int lane = t & 63;
    int w = t >> 6;
    int kind = w >> 12;                       // NB = 4096 = 2^12
    int b = w & (NB - 1);
    if (kind < 2) {
        int r = (kind == 0) ? uids[b] : ulocs[b];
        int b0 = rp_u[r], b1 = rp_u[r + 1];
        float agg = 0.f;
        for (int j = b0; j < b1; ++j) {
            int c = cl_u[j];
            agg += ci1[(long long)c * DD + lane];
        }
        float val = ue_k[(long long)r * DD + lane]
                  + 2.f * cu1[(long long)r * DD + lane] + lrelu(agg);
        float* dst = (kind == 0) ? su : sl;
        dst[b * DD + lane] += val;
    } else {
        int r = iids[b];
        int b0 = rp_i[r], b1 = rp_i[r + 1];
        float agg = 0.f;
        for (int j = b0; j < b1; ++j) {
            int c = cl_i[j];
            agg += cu1[(long long)c * DD + lane];
        }
        float val = ie_k[(long long)r * DD + lane]
                  + 2.f * ci1[(long long)r * DD + lane] + lrelu(agg);
        si[b * DD + lane] += val;
    }
}

// preds[b] = dot(su,si)/16 + dot(lrelu(sl), si)/4; wave-64 reduction per b.
__global__ __launch_bounds__(256) void final_kern(const float* __restrict__ su,
                                                  const float* __restrict__ sl,
                                                  const float* __restrict__ si,
                                                  float* __restrict__ out) {
    int t = blockIdx.x * 256 + threadIdx.x;   // NB*DD threads
    int b = t >> 6;
    float s_i = si[t];
    float p = su[t] * s_i * (1.0f / 16.0f) + lrelu(sl[t]) * s_i * 0.25f;
    #pragma unroll
    for (int off = 32; off >= 1; off >>= 1) p += __shfl_down(p, off);
    if ((t & 63) == 0) out[b] = p;
}

extern "C" void kernel_launch(void* const* d_in, const int* in_sizes, int n_in,
                              void* d_out, int out_size, void* d_ws, size_t ws_size,
                              hipStream_t stream) {
    (void)in_sizes; (void)n_in; (void)out_size; (void)ws_size;

    const float* ue     = (const float*)d_in[0];  // [G,U,D]
    const float* ie     = (const float*)d_in[1];  // [G,I,D]
    const int*   sa_src = (const int*)d_in[2];    // [G,NNZ] item idx (sources)
    const int*   sa_tgt = (const int*)d_in[3];    // [G,NNZ] user idx (targets)
    const int*   st_src = (const int*)d_in[4];    // [G,NNZ] user idx (sources)
    const int*   st_tgt = (const int*)d_in[5];    // [G,NNZ] item idx (targets)
    const int*   uids   = (const int*)d_in[6];    // [B]
    const int*   iids   = (const int*)d_in[7];    // [B]
    const int*   ulocs  = (const int*)d_in[8];    // [B]

    // workspace layout (~122 MB)
    char* p = (char*)d_ws;
    float* cu1  = (float*)p;                 p += sizeof(float) * (size_t)NU * DD;       // 51.2 MB
    float* ci1  = (float*)p;                 p += sizeof(float) * (size_t)NI * DD;       // 25.6 MB
    float* su   = (float*)p;                 p += sizeof(float) * (size_t)NB * DD;
    float* sl   = (float*)p;                 p += sizeof(float) * (size_t)NB * DD;
    float* si   = (float*)p;                 p += sizeof(float) * (size_t)NB * DD;       // 3.1 MB
    int*   rp_u = (int*)p;                   p += sizeof(int) * (size_t)NG * (NU + 1);   // 3.2 MB
    int*   rp_i = (int*)p;                   p += sizeof(int) * (size_t)NG * (NI + 1);   // 1.6 MB
    int*   cnt_u= (int*)p;                   p += sizeof(int) * (size_t)NG * NU;         // 3.2 MB
    int*   cnt_i= (int*)p;                   p += sizeof(int) * (size_t)NG * NI;         // 1.6 MB  (contiguous with cnt_u)
    int*   cl_u = (int*)p;                   p += sizeof(int) * (size_t)NG * NNZE;       // 16 MB
    int*   cl_i = (int*)p;                   p += sizeof(int) * (size_t)NG * NNZE;       // 16 MB
    int*   csum = (int*)p;                   p += sizeof(int) * (size_t)NCHUNKS;

    const int edgeBlocks = (int)((2LL * NG * NNZE) / 256);      // 31250
    const int l1Blocks   = (int)(((size_t)(NU + NI) * DD) / 256); // 75000
    const int sampBlocks = (3 * NB * DD) / 256;                  // 3072
    const int finBlocks  = (NB * DD) / 256;                      // 1024

    // zero counters + batch accumulators
    hipMemsetAsync(cnt_u, 0, sizeof(int) * (size_t)NG * (NU + NI), stream);
    hipMemsetAsync(su, 0, sizeof(float) * (size_t)3 * NB * DD, stream);

    // CSR build (all graphs, both directions)
    hist_kern<<<edgeBlocks, 256, 0, stream>>>(sa_tgt, st_tgt, cnt_u, cnt_i);
    scan1_kern<<<NCHUNKS, 256, 0, stream>>>(cnt_u, cnt_i, csum);
    scan2_kern<<<2 * NG, 256, 0, stream>>>(csum, rp_u, rp_i);
    scan3_kern<<<NCHUNKS, 256, 0, stream>>>(cnt_u, cnt_i, csum, rp_u, rp_i);
    hipMemsetAsync(cnt_u, 0, sizeof(int) * (size_t)NG * (NU + NI), stream);
    fill_kern<<<edgeBlocks, 256, 0, stream>>>(sa_src, sa_tgt, st_src, st_tgt,
                                              rp_u, rp_i, cnt_u, cnt_i, cl_u, cl_i);

    for (int g = 0; g < NG; ++g) {
        const float* ue_k = ue + (size_t)g * NU * DD;
        const float* ie_k = ie + (size_t)g * NI * DD;
        const int* rpu_g = rp_u + (size_t)g * (NU + 1);
        const int* rpi_g = rp_i + (size_t)g * (NI + 1);
        const int* clu_g = cl_u + (size_t)g * NNZE;
        const int* cli_g = cl_i + (size_t)g * NNZE;

        layer1_kern<<<l1Blocks, 256, 0, stream>>>(ue_k, ie_k, rpu_g, rpi_g,
                                                  clu_g, cli_g, cu1, ci1);
        samp_kern<<<sampBlocks, 256, 0, stream>>>(ue_k, ie_k, rpu_g, rpi_g,
                                                  clu_g, cli_g, cu1, ci1,
                                                  uids, iids, ulocs, su, si, sl);
    }

    final_kern<<<finBlocks, 256, 0, stream>>>(su, sl, si, (float*)d_out);
}

// Round 14
// 1550.526 us; speedup vs baseline: 2.7422x; 1.2975x over previous
//
#include <hip/hip_runtime.h>

// Problem constants (match reference)
#define NG   4
#define NU   200000
#define NI   100000
#define DD   64
#define NNZE 1000000
#define NB   4096

// scan chunking
#define CH      256
#define CHU     ((NU + CH - 1) / CH)        // 782 chunks per user array
#define CHI     ((NI + CH - 1) / CH)        // 391 chunks per item array
#define NCHUNKS (NG * CHU + NG * CHI)       // 4692

// edges-per-thread for hist/fill
#define EPT  4
#define SLOTS_PER_STREAM (NNZE / EPT)       // 250000
#define EDGE_THREADS (2 * NG * SLOTS_PER_STREAM)   // 2,000,000 (NOT /256-exact!)

__device__ __forceinline__ float lrelu(float x) { return fmaxf(x, 0.5f * x); }

// ---------------- CSR build ----------------
// hist/fill: each thread owns EPT=4 consecutive edges of one (graph,dir) stream.
// stream = tid / SLOTS_PER_STREAM; g = stream>>1; dir = stream&1.
// TAIL GUARD REQUIRED: EDGE_THREADS % 256 != 0; unguarded tail threads compute
// stream=8 -> g=4 and corrupt cnt_i / cl_* (round-11 absmax=3351 bug).

__global__ __launch_bounds__(256) void hist_kern(const int* __restrict__ sa_tgt,
                                                 const int* __restrict__ st_tgt,
                                                 int* __restrict__ cnt_u,
                                                 int* __restrict__ cnt_i) {
    int tid = blockIdx.x * 256 + threadIdx.x;           // [0, EDGE_THREADS)
    if (tid >= EDGE_THREADS) return;
    int stream = tid / SLOTS_PER_STREAM;
    int off = (tid - stream * SLOTS_PER_STREAM) * EPT;
    int g = stream >> 1;
    const int* tgt; int* cnt; long long cbase;
    if ((stream & 1) == 0) { tgt = sa_tgt; cnt = cnt_u; cbase = (long long)g * NU; }
    else                   { tgt = st_tgt; cnt = cnt_i; cbase = (long long)g * NI; }
    int4 t4 = *reinterpret_cast<const int4*>(tgt + (long long)g * NNZE + off);
    atomicAdd(&cnt[cbase + t4.x], 1);
    atomicAdd(&cnt[cbase + t4.y], 1);
    atomicAdd(&cnt[cbase + t4.z], 1);
    atomicAdd(&cnt[cbase + t4.w], 1);
}

// per-chunk sums
__global__ __launch_bounds__(256) void scan1_kern(const int* __restrict__ cnt_u,
                                                  const int* __restrict__ cnt_i,
                                                  int* __restrict__ csum) {
    int cb = blockIdx.x, tid = threadIdx.x;
    const int* arr; int N, local;
    if (cb < NG * CHU) {
        int a = cb / CHU; local = cb - a * CHU;
        arr = cnt_u + (long long)a * NU; N = NU;
    } else {
        int c2 = cb - NG * CHU;
        int a = c2 / CHI; local = c2 - a * CHI;
        arr = cnt_i + (long long)a * NI; N = NI;
    }
    int idx = local * CH + tid;
    int v = (idx < N) ? arr[idx] : 0;
    __shared__ int sh[256];
    sh[tid] = v; __syncthreads();
    for (int off = 128; off > 0; off >>= 1) {
        if (tid < off) sh[tid] += sh[tid + off];
        __syncthreads();
    }
    if (tid == 0) csum[cb] = sh[0];
}

// exclusive-scan the chunk sums of each of the 8 arrays; write rp[N] = total
__global__ __launch_bounds__(256) void scan2_kern(int* __restrict__ csum,
                                                  int* __restrict__ rp_u,
                                                  int* __restrict__ rp_i) {
    int a = blockIdx.x, tid = threadIdx.x;
    int base, nc; int* rpN;
    if (a < NG) { base = a * CHU; nc = CHU; rpN = rp_u + (long long)a * (NU + 1) + NU; }
    else        { base = NG * CHU + (a - NG) * CHI; nc = CHI;
                  rpN = rp_i + (long long)(a - NG) * (NI + 1) + NI; }
    __shared__ int sh[256];
    int carry = 0;
    for (int t0 = 0; t0 < nc; t0 += 256) {
        int i = t0 + tid;
        int v = (i < nc) ? csum[base + i] : 0;
        sh[tid] = v; __syncthreads();
        for (int off = 1; off < 256; off <<= 1) {
            int t = (tid >= off) ? sh[tid - off] : 0;
            __syncthreads();
            sh[tid] += t;
            __syncthreads();
        }
        int incl = sh[tid];
        int total = sh[255];
        if (i < nc) csum[base + i] = incl - v + carry;
        carry += total;
        __syncthreads();
    }
    if (tid == 0) *rpN = carry;
}

// row_ptr[idx] = scanned_chunk_offset + intra-chunk exclusive prefix
__global__ __launch_bounds__(256) void scan3_kern(const int* __restrict__ cnt_u,
                                                  const int* __restrict__ cnt_i,
                                                  const int* __restrict__ csum,
                                                  int* __restrict__ rp_u,
                                                  int* __restrict__ rp_i) {
    int cb = blockIdx.x, tid = threadIdx.x;
    const int* arr; int* rp; int N, local;
    if (cb < NG * CHU) {
        int a = cb / CHU; local = cb - a * CHU;
        arr = cnt_u + (long long)a * NU; rp = rp_u + (long long)a * (NU + 1); N = NU;
    } else {
        int c2 = cb - NG * CHU;
        int a = c2 / CHI; local = c2 - a * CHI;
        arr = cnt_i + (long long)a * NI; rp = rp_i + (long long)a * (NI + 1); N = NI;
    }
    int idx = local * CH + tid;
    int v = (idx < N) ? arr[idx] : 0;
    __shared__ int sh[256];
    sh[tid] = v; __syncthreads();
    for (int off = 1; off < 256; off <<= 1) {
        int t = (tid >= off) ? sh[tid - off] : 0;
        __syncthreads();
        sh[tid] += t;
        __syncthreads();
    }
    if (idx < N) rp[idx] = csum[cb] + sh[tid] - v;
}

// scatter edge sources into CSR col arrays (cnt_* re-zeroed as cursors);
// EPT=4 edges per thread -> 4 independent latency chains.
__global__ __launch_bounds__(256) void fill_kern(const int* __restrict__ sa_src,
                                                 const int* __restrict__ sa_tgt,
                                                 const int* __restrict__ st_src,
                                                 const int* __restrict__ st_tgt,
                                                 const int* __restrict__ rp_u,
                                                 const int* __restrict__ rp_i,
                                                 int* __restrict__ cnt_u,
                                                 int* __restrict__ cnt_i,
                                                 int* __restrict__ cl_u,
                                                 int* __restrict__ cl_i) {
    int tid = blockIdx.x * 256 + threadIdx.x;
    if (tid >= EDGE_THREADS) return;
    int stream = tid / SLOTS_PER_STREAM;
    int off = (tid - stream * SLOTS_PER_STREAM) * EPT;
    int g = stream >> 1;
    const int* tgt; const int* src; const int* rp; int* cnt; int* cl;
    long long cbase, rbase;
    if ((stream & 1) == 0) {
        tgt = sa_tgt; src = sa_src; rp = rp_u; cnt = cnt_u; cl = cl_u;
        cbase = (long long)g * NU; rbase = (long long)g * (NU + 1);
    } else {
        tgt = st_tgt; src = st_src; rp = rp_i; cnt = cnt_i; cl = cl_i;
        cbase = (long long)g * NI; rbase = (long long)g * (NI + 1);
    }
    long long ebase = (long long)g * NNZE + off;
    int4 t4 = *reinterpret_cast<const int4*>(tgt + ebase);
    int4 s4 = *reinterpret_cast<const int4*>(src + ebase);
    // 4 independent chains; compiler can overlap the atomics and rp loads
    int o0 = atomicAdd(&cnt[cbase + t4.x], 1);
    int o1 = atomicAdd(&cnt[cbase + t4.y], 1);
    int o2 = atomicAdd(&cnt[cbase + t4.z], 1);
    int o3 = atomicAdd(&cnt[cbase + t4.w], 1);
    int p0 = rp[rbase + t4.x] + o0;
    int p1 = rp[rbase + t4.y] + o1;
    int p2 = rp[rbase + t4.z] + o2;
    int p3 = rp[rbase + t4.w] + o3;
    long long clbase = (long long)g * NNZE;
    cl[clbase + p0] = s4.x;
    cl[clbase + p1] = s4.y;
    cl[clbase + p2] = s4.z;
    cl[clbase + p3] = s4.w;
}

// ---------------- layer 1: gather-aggregate, fused lrelu+residual ----------------
// 16 lanes per row, float4 per lane; each wave processes 4 rows (4 chains),
// neighbor loop unrolled by 2 -> up to 8 outstanding gathers per wave.
// rows [0,NU) = users, [NU,NU+NI) = items.  (NU % 4 == 0 so groups never straddle.)
__global__ __launch_bounds__(256) void layer1_kern(const float* __restrict__ ue_k,
                                                   const float* __restrict__ ie_k,
                                                   const int* __restrict__ rp_u,
                                                   const int* __restrict__ rp_i,
                                                   const int* __restrict__ cl_u,
                                                   const int* __restrict__ cl_i,
                                                   float* __restrict__ cu1,
                                                   float* __restrict__ ci1) {
    int t = blockIdx.x * 256 + threadIdx.x;
    int lane = t & 63;
    int group = lane >> 4;          // 0..3
    int l16 = lane & 15;            // dim quarter: floats [l16*4, l16*4+4)
    long long w = (long long)(t >> 6);
    long long row = w * 4 + group;  // [0, NU+NI)
    const float* srcTab; const float* resTab; float* dst;
    const int* rp; const int* cl; int r;
    if (row < NU) {
        r = (int)row; rp = rp_u; cl = cl_u; srcTab = ie_k; resTab = ue_k; dst = cu1;
    } else if (row < (long long)NU + NI) {
        r = (int)(row - NU); rp = rp_i; cl = cl_i; srcTab = ue_k; resTab = ie_k; dst = ci1;
    } else return;
    int b0 = rp[r], b1 = rp[r + 1];
    float4 acc = make_float4(0.f, 0.f, 0.f, 0.f);
    int j = b0;
    for (; j + 1 < b1; j += 2) {
        int c0 = cl[j], c1 = cl[j + 1];
        float4 v0 = *reinterpret_cast<const float4*>(srcTab + (long long)c0 * DD + l16 * 4);
        float4 v1 = *reinterpret_cast<const float4*>(srcTab + (long long)c1 * DD + l16 * 4);
        acc.x += v0.x + v1.x; acc.y += v0.y + v1.y;
        acc.z += v0.z + v1.z; acc.w += v0.w + v1.w;
    }
    if (j < b1) {
        int c0 = cl[j];
        float4 v0 = *reinterpret_cast<const float4*>(srcTab + (long long)c0 * DD + l16 * 4);
        acc.x += v0.x; acc.y += v0.y; acc.z += v0.z; acc.w += v0.w;
    }
    float4 res = *reinterpret_cast<const float4*>(resTab + (long long)r * DD + l16 * 4);
    float4 outv;
    outv.x = lrelu(acc.x) + res.x; outv.y = lrelu(acc.y) + res.y;
    outv.z = lrelu(acc.z) + res.z; outv.w = lrelu(acc.w) + res.w;
    *reinterpret_cast<float4*>(dst + (long long)r * DD + l16 * 4) = outv;
}

// ---------------- layer 2 at sampled rows only, + accumulate ----------------
// sum over stages = e0 + 2*e1 + lrelu(agg2); 4 rows per wave, float4 per lane.
// sample idx in [0, 3*NB): kind = idx>>12 (0->su/uids, 1->sl/ulocs, 2->si/iids)
__global__ __launch_bounds__(256) void samp_kern(const float* __restrict__ ue_k,
                                                 const float* __restrict__ ie_k,
                                                 const int* __restrict__ rp_u,
                                                 const int* __restrict__ rp_i,
                                                 const int* __restrict__ cl_u,
                                                 const int* __restrict__ cl_i,
                                                 const float* __restrict__ cu1,
                                                 const float* __restrict__ ci1,
                                                 const int* __restrict__ uids,
                                                 const int* __restrict__ iids,
                                                 const int* __restrict__ ulocs,
                                                 float* __restrict__ su,
                                                 float* __restrict__ si,
                                                 float* __restrict__ sl) {
    int t = blockIdx.x * 256 + threadIdx.x;   // 3*NB/4 waves * 64 lanes
    int lane = t & 63;
    int group = lane >> 4, l16 = lane & 15;
    int idx = (t >> 6) * 4 + group;           // [0, 3*NB)
    if (idx >= 3 * NB) return;
    int kind = idx >> 12;                     // NB = 4096 = 2^12
    int b = idx & (NB - 1);
    const int* rp; const int* cl; const float* gatherTab;
    const float* e0Tab; const float* e1Tab; float* dst; int r;
    if (kind == 0)      { r = uids[b];  rp = rp_u; cl = cl_u; gatherTab = ci1; e0Tab = ue_k; e1Tab = cu1; dst = su; }
    else if (kind == 1) { r = ulocs[b]; rp = rp_u; cl = cl_u; gatherTab = ci1; e0Tab = ue_k; e1Tab = cu1; dst = sl; }
    else                { r = iids[b];  rp = rp_i; cl = cl_i; gatherTab = cu1; e0Tab = ie_k; e1Tab = ci1; dst = si; }
    int b0 = rp[r], b1 = rp[r + 1];
    float4 agg = make_float4(0.f, 0.f, 0.f, 0.f);
    int j = b0;
    for (; j + 1 < b1; j += 2) {
        int c0 = cl[j], c1 = cl[j + 1];
        float4 v0 = *reinterpret_cast<const float4*>(gatherTab + (long long)c0 * DD + l16 * 4);
        float4 v1 = *reinterpret_cast<const float4*>(gatherTab + (long long)c1 * DD + l16 * 4);
        agg.x += v0.x + v1.x; agg.y += v0.y + v1.y;
        agg.z += v0.z + v1.z; agg.w += v0.w + v1.w;
    }
    if (j < b1) {
        int c0 = cl[j];
        float4 v0 = *reinterpret_cast<const float4*>(gatherTab + (long long)c0 * DD + l16 * 4);
        agg.x += v0.x; agg.y += v0.y; agg.z += v0.z; agg.w += v0.w;
    }
    float4 e0 = *reinterpret_cast<const float4*>(e0Tab + (long long)r * DD + l16 * 4);
    float4 e1 = *reinterpret_cast<const float4*>(e1Tab + (long long)r * DD + l16 * 4);
    float4* dp = reinterpret_cast<float4*>(dst + (long long)b * DD + l16 * 4);
    float4 d = *dp;
    d.x += e0.x + 2.f * e1.x + lrelu(agg.x);
    d.y += e0.y + 2.f * e1.y + lrelu(agg.y);
    d.z += e0.z + 2.f * e1.z + lrelu(agg.z);
    d.w += e0.w + 2.f * e1.w + lrelu(agg.w);
    *dp = d;
}

// preds[b] = dot(su,si)/16 + dot(lrelu(sl), si)/4; wave-64 reduction per b.
__global__ __launch_bounds__(256) void final_kern(const float* __restrict__ su,
                                                  const float* __restrict__ sl,
                                                  const float* __restrict__ si,
                                                  float* __restrict__ out) {
    int t = blockIdx.x * 256 + threadIdx.x;   // NB*DD threads
    int b = t >> 6;
    float s_i = si[t];
    float p = su[t] * s_i * (1.0f / 16.0f) + lrelu(sl[t]) * s_i * 0.25f;
    #pragma unroll
    for (int off = 32; off >= 1; off >>= 1) p += __shfl_down(p, off);
    if ((t & 63) == 0) out[b] = p;
}

extern "C" void kernel_launch(void* const* d_in, const int* in_sizes, int n_in,
                              void* d_out, int out_size, void* d_ws, size_t ws_size,
                              hipStream_t stream) {
    (void)in_sizes; (void)n_in; (void)out_size; (void)ws_size;

    const float* ue     = (const float*)d_in[0];  // [G,U,D]
    const float* ie     = (const float*)d_in[1];  // [G,I,D]
    const int*   sa_src = (const int*)d_in[2];    // [G,NNZ] item idx (sources)
    const int*   sa_tgt = (const int*)d_in[3];    // [G,NNZ] user idx (targets)
    const int*   st_src = (const int*)d_in[4];    // [G,NNZ] user idx (sources)
    const int*   st_tgt = (const int*)d_in[5];    // [G,NNZ] item idx (targets)
    const int*   uids   = (const int*)d_in[6];    // [B]
    const int*   iids   = (const int*)d_in[7];    // [B]
    const int*   ulocs  = (const int*)d_in[8];    // [B]

    // workspace layout (~122 MB)
    char* p = (char*)d_ws;
    float* cu1  = (float*)p;                 p += sizeof(float) * (size_t)NU * DD;       // 51.2 MB
    float* ci1  = (float*)p;                 p += sizeof(float) * (size_t)NI * DD;       // 25.6 MB
    float* su   = (float*)p;                 p += sizeof(float) * (size_t)NB * DD;
    float* sl   = (float*)p;                 p += sizeof(float) * (size_t)NB * DD;
    float* si   = (float*)p;                 p += sizeof(float) * (size_t)NB * DD;       // 3.1 MB
    int*   rp_u = (int*)p;                   p += sizeof(int) * (size_t)NG * (NU + 1);   // 3.2 MB
    int*   rp_i = (int*)p;                   p += sizeof(int) * (size_t)NG * (NI + 1);   // 1.6 MB
    int*   cnt_u= (int*)p;                   p += sizeof(int) * (size_t)NG * NU;         // 3.2 MB
    int*   cnt_i= (int*)p;                   p += sizeof(int) * (size_t)NG * NI;         // 1.6 MB  (contiguous with cnt_u)
    int*   cl_u = (int*)p;                   p += sizeof(int) * (size_t)NG * NNZE;       // 16 MB
    int*   cl_i = (int*)p;                   p += sizeof(int) * (size_t)NG * NNZE;       // 16 MB
    int*   csum = (int*)p;                   p += sizeof(int) * (size_t)NCHUNKS;

    const int edgeBlocksC = (EDGE_THREADS + 255) / 256;          // 7813 (tail guarded)
    const int l1Blocks    = (int)(((size_t)(NU + NI) / 4 * 64 + 255) / 256); // 18750
    const int sampBlocks  = ((3 * NB / 4) * 64 + 255) / 256;     // 768
    const int finBlocks   = (NB * DD) / 256;                     // 1024

    // zero counters + batch accumulators
    hipMemsetAsync(cnt_u, 0, sizeof(int) * (size_t)NG * (NU + NI), stream);
    hipMemsetAsync(su, 0, sizeof(float) * (size_t)3 * NB * DD, stream);

    // CSR build (all graphs, both directions)
    hist_kern<<<edgeBlocksC, 256, 0, stream>>>(sa_tgt, st_tgt, cnt_u, cnt_i);
    scan1_kern<<<NCHUNKS, 256, 0, stream>>>(cnt_u, cnt_i, csum);
    scan2_kern<<<2 * NG, 256, 0, stream>>>(csum, rp_u, rp_i);
    scan3_kern<<<NCHUNKS, 256, 0, stream>>>(cnt_u, cnt_i, csum, rp_u, rp_i);
    hipMemsetAsync(cnt_u, 0, sizeof(int) * (size_t)NG * (NU + NI), stream);
    fill_kern<<<edgeBlocksC, 256, 0, stream>>>(sa_src, sa_tgt, st_src, st_tgt,
                                               rp_u, rp_i, cnt_u, cnt_i, cl_u, cl_i);

    for (int g = 0; g < NG; ++g) {
        const float* ue_k = ue + (size_t)g * NU * DD;
        const float* ie_k = ie + (size_t)g * NI * DD;
        const int* rpu_g = rp_u + (size_t)g * (NU + 1);
        const int* rpi_g = rp_i + (size_t)g * (NI + 1);
        const int* clu_g = cl_u + (size_t)g * NNZE;
        const int* cli_g = cl_i + (size_t)g * NNZE;

        layer1_kern<<<l1Blocks, 256, 0, stream>>>(ue_k, ie_k, rpu_g, rpi_g,
                                                  clu_g, cli_g, cu1, ci1);
        samp_kern<<<sampBlocks, 256, 0, stream>>>(ue_k, ie_k, rpu_g, rpi_g,
                                                  clu_g, cli_g, cu1, ci1,
                                                  uids, iids, ulocs, su, si, sl);
    }

    final_kern<<<finBlocks, 256, 0, stream>>>(su, sl, si, (float*)d_out);
}